// Round 8
// baseline (458.371 us; speedup 1.0000x reference)
//
#include <hip/hip_runtime.h>
#include <hip/hip_bf16.h>

// ---------------------------------------------------------------------------
// AttentionMIL: x[16,4096,1024] -> Linear+LN+ReLU -> Linear+LN+ReLU ->
//               attention (tanh linear -> scalar -> softmax over N) ->
//               weighted pool -> 2-layer classifier -> logits [16,2]
//
// Round 8: 128x128 tile, BK=32, 4 waves, chunk-swizzled LDS (0 conflicts),
// 3-deep LDS ring (48KB -> 3 blocks/CU) with counted vmcnt: tile t's loads
// issued at step t-3, waited at step t via vmcnt(8)/(12) -- never drained to
// 0 in the main loop; raw s_barrier only. De-fused LN via partial stats.
// ---------------------------------------------------------------------------

#define MTOT   65536
#define DDIM   1024
#define HDIM   512
#define NBAG   16
#define NINST  4096

typedef __attribute__((ext_vector_type(8))) short bf16x8;
typedef __attribute__((ext_vector_type(4))) float f32x4;

__device__ __forceinline__ unsigned short f2bf(float f) {
  __hip_bfloat16 h = __float2bfloat16(f);
  unsigned short u;
  __builtin_memcpy(&u, &h, 2);
  return u;
}
__device__ __forceinline__ float bf2f(unsigned short u) {
  unsigned int x = ((unsigned int)u) << 16;
  float f;
  __builtin_memcpy(&f, &x, 4);
  return f;
}

__device__ __forceinline__ void gload16(const void* g, void* l) {
  __builtin_amdgcn_global_load_lds(
      (const __attribute__((address_space(1))) unsigned int*)g,
      (__attribute__((address_space(3))) unsigned int*)l, 16, 0, 0);
}

__device__ __forceinline__ bf16x8 pack8(float4 a, float4 b) {
  bf16x8 r;
  r[0] = (short)f2bf(a.x); r[1] = (short)f2bf(a.y);
  r[2] = (short)f2bf(a.z); r[3] = (short)f2bf(a.w);
  r[4] = (short)f2bf(b.x); r[5] = (short)f2bf(b.y);
  r[6] = (short)f2bf(b.z); r[7] = (short)f2bf(b.w);
  return r;
}

#define VMW(N)  asm volatile("s_waitcnt vmcnt(" #N ")" ::: "memory")
#define LKW0    asm volatile("s_waitcnt lgkmcnt(0)" ::: "memory")
#define SB0     __builtin_amdgcn_sched_barrier(0)
#define BARRIER __builtin_amdgcn_s_barrier()

// ---------------------------------------------------------------------------
// transpose + cast f32 [R][C] -> bf16 [C][R]
// ---------------------------------------------------------------------------
__global__ void transpose_cast(const float* __restrict__ src,
                               __hip_bfloat16* __restrict__ dst,
                               int R, int C) {
  __shared__ float t[32][33];
  const int c0 = blockIdx.x * 32, r0 = blockIdx.y * 32;
  const int tx = threadIdx.x, ty = threadIdx.y;  // 32 x 8
#pragma unroll
  for (int i = 0; i < 32; i += 8)
    t[ty + i][tx] = src[(size_t)(r0 + ty + i) * C + c0 + tx];
  __syncthreads();
#pragma unroll
  for (int i = 0; i < 32; i += 8)
    dst[(size_t)(c0 + ty + i) * R + r0 + tx] = __float2bfloat16(t[tx][ty + i]);
}

// ---------------------------------------------------------------------------
// GEMM tile kernel: C-tile(128x128) = A[128 x KD] * BT-panel(128 rows)^T
// 256 threads, 4 waves (2M x 2N), frag 4x4 (acc 64 VGPR), BK=32.
// LDS ring: 3 x (A 8KB + B 8KB). Chunk = 16 rows x 32 k (1KB); lane l holds
// (row l&15, kslot (l>>4)^(l&3)) at byte 16l (linear gload_lds dest +
// pre-swizzled source; 0 bank conflicts, round-5/6 verified).
// Step t: vmcnt(8|12) [tile t landed] -> bar -> ds_read frags -> lgkm0 ->
// bar [all reads done] -> issue tile t+3 into buf t%3 -> setprio MFMA.
// MODE 0: z bf16 out + per-row partial (sum,sumsq) -> statp[row][4]
// MODE 1: per-row partial sum tanh(z)*wa2 -> scorep[row][4]
// ---------------------------------------------------------------------------
#define BM 128
#define BN 128
#define BK 32

template <int KD, bool AF32, int MODE>
__global__ __launch_bounds__(256, AF32 ? 2 : 3)
void gemm_tile(const void* Ap, const __hip_bfloat16* __restrict__ BT,
               const float* __restrict__ bias,
               __hip_bfloat16* __restrict__ ybuf,
               float2* __restrict__ statp,
               const float* __restrict__ wa2,
               float* __restrict__ scorep) {
  __shared__ __align__(16) char smem[49152];  // 3 ring bufs x (A 8KB | B 8KB)

  const int tid  = threadIdx.x;     // 256
  const int lane = tid & 63;
  const int w    = tid >> 6;        // 4 waves
  const int wm   = w >> 1;          // 0..1
  const int wn   = w & 1;           // 0..1
  const int l16  = lane & 15;
  const int lg   = lane >> 4;       // 0..3

  // XCD-bijective remap (grid 2048 % 8 == 0)
  const int cpx = gridDim.x >> 3;
  int bid = blockIdx.x;
  bid = (bid & 7) * cpx + (bid >> 3);
  const int n_blk   = bid & 3;          // 512 / BN
  const int row_blk = bid >> 2;
  const size_t row0 = (size_t)row_blk * BM;
  const int col0    = n_blk * BN;

  // staging geometry (within 1KB chunk)
  const int rS   = lane & 15;
  const int sS   = (lane >> 4) ^ (lane & 3);
  const int dOff = lane * 8;
  const int frag_off = l16 * 8 + ((lg ^ (l16 & 3)) << 7);

  constexpr int NT = KD / BK;  // 32 (GEMM1) / 16 (GEMM2,3)
  const __hip_bfloat16* Abf = (const __hip_bfloat16*)Ap;
  const float* Af32 = (const float*)Ap;

  f32x4 acc[4][4];
#pragma unroll
  for (int i = 0; i < 4; i++)
#pragma unroll
    for (int j = 0; j < 4; j++) acc[i][j] = (f32x4){0.f, 0.f, 0.f, 0.f};

  auto stageB = [&](int kb, int j) {
#pragma unroll
    for (int i = 0; i < 2; i++) {
      const int c = w * 2 + i;  // chunk 0..7 = 16 BT-rows (output cols)
      gload16(BT + (size_t)(col0 + c * 16 + rS) * KD + kb + sS * 8,
              (__hip_bfloat16*)(smem + j * 16384 + 8192) + c * 512 + dOff);
    }
  };
  auto stageA = [&](int kb, int j) {
#pragma unroll
    for (int i = 0; i < 2; i++) {
      const int c = w * 2 + i;
      gload16(Abf + (row0 + c * 16 + rS) * KD + kb + sS * 8,
              (__hip_bfloat16*)(smem + j * 16384) + c * 512 + dOff);
    }
  };

#define LOADA_(SET, KB)                                                        \
  _Pragma("unroll") for (int i_ = 0; i_ < 2; i_++) {                           \
    const float* gp_ =                                                         \
        Af32 + (row0 + (w * 2 + i_) * 16 + rS) * KD + (KB) + sS * 8;           \
    SET[i_ * 2 + 0] = *(const float4*)gp_;                                     \
    SET[i_ * 2 + 1] = *(const float4*)(gp_ + 4);                               \
  }
#define CVTW_(SET, J)                                                          \
  _Pragma("unroll") for (int i_ = 0; i_ < 2; i_++)                             \
    *reinterpret_cast<bf16x8*>((__hip_bfloat16*)(smem + (J) * 16384) +         \
                               (w * 2 + i_) * 512 + dOff) =                    \
        pack8(SET[i_ * 2 + 0], SET[i_ * 2 + 1]);

#define FRAGS_(J)                                                              \
  _Pragma("unroll") for (int f_ = 0; f_ < 4; f_++)                             \
      af[f_] = *reinterpret_cast<const bf16x8*>(                               \
          (__hip_bfloat16*)(smem + (J) * 16384) + (wm * 4 + f_) * 512 +        \
          frag_off);                                                           \
  _Pragma("unroll") for (int f_ = 0; f_ < 4; f_++)                             \
      bfr[f_] = *reinterpret_cast<const bf16x8*>(                              \
          (__hip_bfloat16*)(smem + (J) * 16384 + 8192) + (wn * 4 + f_) * 512 + \
          frag_off);

#define MFMAS_                                                                 \
  _Pragma("unroll") for (int fm_ = 0; fm_ < 4; fm_++)                          \
  _Pragma("unroll") for (int fn_ = 0; fn_ < 4; fn_++)                          \
      acc[fm_][fn_] = __builtin_amdgcn_mfma_f32_16x16x32_bf16(                 \
          af[fm_], bfr[fn_], acc[fm_][fn_], 0, 0, 0);

  // bf16-A step: 4 loads/tile in flight-groups; VMW(8)=3-step gap
#define STEP_G(J, T, VMN)                                                      \
  {                                                                            \
    VMW(VMN);                                                                  \
    BARRIER;                                                                   \
    bf16x8 af[4], bfr[4];                                                      \
    FRAGS_(J);                                                                 \
    LKW0; SB0;                                                                 \
    BARRIER;                                                                   \
    if ((T) + 3 < NT) {                                                        \
      stageA(((T) + 3) * BK, (J));                                             \
      stageB(((T) + 3) * BK, (J));                                             \
    }                                                                          \
    __builtin_amdgcn_s_setprio(1);                                             \
    MFMAS_;                                                                    \
    __builtin_amdgcn_s_setprio(0);                                             \
  }

  // f32-A step: 6 loads/tile (4 reg + 2 lds); cvt+ds_write at consume time
#define STEP_F(J, T, VMN)                                                      \
  {                                                                            \
    VMW(VMN);                                                                  \
    CVTW_(set##J, (J));                                                        \
    LKW0;                                                                      \
    BARRIER;                                                                   \
    bf16x8 af[4], bfr[4];                                                      \
    FRAGS_(J);                                                                 \
    LKW0; SB0;                                                                 \
    BARRIER;                                                                   \
    if ((T) + 3 < NT) {                                                        \
      LOADA_(set##J, ((T) + 3) * BK);                                          \
      stageB(((T) + 3) * BK, (J));                                             \
    }                                                                          \
    __builtin_amdgcn_s_setprio(1);                                             \
    MFMAS_;                                                                    \
    __builtin_amdgcn_s_setprio(0);                                             \
  }

  if constexpr (AF32) {
    float4 set0[4], set1[4], set2[4];
    LOADA_(set0, 0);       stageB(0, 0);
    LOADA_(set1, BK);      stageB(BK, 1);
    LOADA_(set2, 2 * BK);  stageB(2 * BK, 2);
    for (int tb = 0; tb + 5 <= NT; tb += 3) {
      STEP_F(0, tb, 12)
      STEP_F(1, tb + 1, 12)
      STEP_F(2, tb + 2, 12)
    }
    if constexpr (NT % 3 == 1) {
      STEP_F(0, NT - 4, 12)
      STEP_F(1, NT - 3, 12)
      STEP_F(2, NT - 2, 6)
      STEP_F(0, NT - 1, 0)
    } else {  // NT % 3 == 2
      STEP_F(0, NT - 2, 6)
      STEP_F(1, NT - 1, 0)
    }
  } else {
    stageA(0, 0);       stageB(0, 0);
    stageA(BK, 1);      stageB(BK, 1);
    stageA(2 * BK, 2);  stageB(2 * BK, 2);
    for (int tb = 0; tb + 5 <= NT; tb += 3) {
      STEP_G(0, tb, 8)
      STEP_G(1, tb + 1, 8)
      STEP_G(2, tb + 2, 8)
    }
    if constexpr (NT % 3 == 1) {
      STEP_G(0, NT - 4, 8)
      STEP_G(1, NT - 3, 8)
      STEP_G(2, NT - 2, 4)
      STEP_G(0, NT - 1, 0)
    } else {  // NT % 3 == 2
      STEP_G(0, NT - 2, 4)
      STEP_G(1, NT - 1, 0)
    }
  }
#undef STEP_G
#undef STEP_F
#undef LOADA_
#undef CVTW_
#undef FRAGS_
#undef MFMAS_

  // ---------------- epilogue: partial stats / partial scores ----------------
  __syncthreads();
  float* redS = (float*)smem;          // [128][2]
  float* redQ = (float*)smem + 256;    // [128][2]

  float biasv[4];
#pragma unroll
  for (int fn = 0; fn < 4; fn++)
    biasv[fn] = bias[col0 + wn * 64 + fn * 16 + l16];

  if (MODE == 0) {
#pragma unroll
    for (int fm = 0; fm < 4; fm++)
#pragma unroll
      for (int r = 0; r < 4; r++) {
        const int rl = wm * 64 + fm * 16 + lg * 4 + r;
        float s1 = 0.f, s2 = 0.f;
#pragma unroll
        for (int fn = 0; fn < 4; fn++) {
          const float z = acc[fm][fn][r] + biasv[fn];
          s1 += z;
          s2 += z * z;
          ybuf[(row0 + rl) * HDIM + col0 + wn * 64 + fn * 16 + l16] =
              __float2bfloat16(z);
        }
#pragma unroll
        for (int m = 1; m < 16; m <<= 1) {
          s1 += __shfl_xor(s1, m);
          s2 += __shfl_xor(s2, m);
        }
        if (l16 == 0) {
          redS[rl * 2 + wn] = s1;
          redQ[rl * 2 + wn] = s2;
        }
      }
    __syncthreads();
    if (tid < BM) {
      statp[(row0 + tid) * 4 + n_blk] =
          make_float2(redS[tid * 2] + redS[tid * 2 + 1],
                      redQ[tid * 2] + redQ[tid * 2 + 1]);
    }
  } else {
    float wv[4];
#pragma unroll
    for (int fn = 0; fn < 4; fn++)
      wv[fn] = wa2[col0 + wn * 64 + fn * 16 + l16];
#pragma unroll
    for (int fm = 0; fm < 4; fm++)
#pragma unroll
      for (int r = 0; r < 4; r++) {
        const int rl = wm * 64 + fm * 16 + lg * 4 + r;
        float s = 0.f;
#pragma unroll
        for (int fn = 0; fn < 4; fn++) {
          const float z = acc[fm][fn][r] + biasv[fn];
          s += tanhf(z) * wv[fn];
        }
#pragma unroll
        for (int m = 1; m < 16; m <<= 1) s += __shfl_xor(s, m);
        if (l16 == 0) redS[rl * 2 + wn] = s;
      }
    __syncthreads();
    if (tid < BM) {
      scorep[(row0 + tid) * 4 + n_blk] = redS[tid * 2] + redS[tid * 2 + 1];
    }
  }
}

// ---------------------------------------------------------------------------
// ln_apply: h[r][c] = relu((y[r][c] - mu_r) * rs_r * g[c] + be[c]), in-place.
// ---------------------------------------------------------------------------
__global__ __launch_bounds__(256)
void ln_apply(__hip_bfloat16* __restrict__ y,
              const float2* __restrict__ statp,
              const float* __restrict__ g, const float* __restrict__ be) {
  const int row = blockIdx.x * 4 + (threadIdx.x >> 6);
  const int c0 = (threadIdx.x & 63) * 8;
  const float2* sp = statp + (size_t)row * 4;
  float S = 0.f, Q = 0.f;
#pragma unroll
  for (int j = 0; j < 4; j++) {
    const float2 p = sp[j];
    S += p.x;
    Q += p.y;
  }
  const float mu = S * (1.f / 512.f);
  const float var = Q * (1.f / 512.f) - mu * mu;
  const float rs = rsqrtf(var + 1e-5f);

  __hip_bfloat16* yp = y + (size_t)row * HDIM + c0;
  bf16x8 v = *reinterpret_cast<const bf16x8*>(yp);
  const float4 ga = *(const float4*)(g + c0), gb = *(const float4*)(g + c0 + 4);
  const float4 ba = *(const float4*)(be + c0), bb = *(const float4*)(be + c0 + 4);
  float gv[8] = {ga.x, ga.y, ga.z, ga.w, gb.x, gb.y, gb.z, gb.w};
  float bv[8] = {ba.x, ba.y, ba.z, ba.w, bb.x, bb.y, bb.z, bb.w};
  bf16x8 o;
#pragma unroll
  for (int j = 0; j < 8; j++) {
    const float f = bf2f((unsigned short)v[j]);
    const float h = fmaxf((f - mu) * rs * gv[j] + bv[j], 0.f);
    o[j] = (short)f2bf(h);
  }
  *reinterpret_cast<bf16x8*>(yp) = o;
}

// ---------------------------------------------------------------------------
// softmax over 4096 instances per bag; input = 4 partial scores per row + ba2
// ---------------------------------------------------------------------------
__global__ void softmax_bag(const float* __restrict__ scorep,
                            const float* __restrict__ ba2,
                            float* __restrict__ at) {
  const int b = blockIdx.x;
  const int tid = threadIdx.x;  // 256
  const int lane = tid & 63, w = tid >> 6;
  const float bv = ba2[0];
  float v[16];
  float mx = -1e30f;
#pragma unroll
  for (int i = 0; i < 16; i++) {
    const float4 sp = *reinterpret_cast<const float4*>(
        scorep + ((size_t)b * NINST + tid + i * 256) * 4);
    v[i] = sp.x + sp.y + sp.z + sp.w + bv;
    mx = fmaxf(mx, v[i]);
  }
#pragma unroll
  for (int off = 32; off; off >>= 1) mx = fmaxf(mx, __shfl_xor(mx, off));
  __shared__ float red[4];
  if (lane == 0) red[w] = mx;
  __syncthreads();
  mx = fmaxf(fmaxf(red[0], red[1]), fmaxf(red[2], red[3]));
  float sum = 0.f;
#pragma unroll
  for (int i = 0; i < 16; i++) {
    v[i] = expf(v[i] - mx);
    sum += v[i];
  }
#pragma unroll
  for (int off = 32; off; off >>= 1) sum += __shfl_xor(sum, off);
  __shared__ float red2[4];
  if (lane == 0) red2[w] = sum;
  __syncthreads();
  sum = red2[0] + red2[1] + red2[2] + red2[3];
  const float inv = 1.f / sum;
#pragma unroll
  for (int i = 0; i < 16; i++) at[(size_t)b * NINST + tid + i * 256] = v[i] * inv;
}

// ---------------------------------------------------------------------------
// pooled[b,h] = sum_n attn[b,n] * h2[b,n,h]
// ---------------------------------------------------------------------------
__global__ void pooled_partial(const __hip_bfloat16* __restrict__ h2,
                               const float* __restrict__ at,
                               float* __restrict__ part) {
  const int bid = blockIdx.x;
  const int b = bid >> 5, cc = (bid >> 3) & 3, nch = bid & 7;
  const int tid = threadIdx.x;  // 256
  const int c4 = (tid & 31) * 4, sub = tid >> 5;
  const int n0 = nch * 512;
  const size_t base = (size_t)b * NINST;
  float a0 = 0.f, a1 = 0.f, a2 = 0.f, a3 = 0.f;
  for (int n = n0 + sub; n < n0 + 512; n += 8) {
    const float a = at[base + n];
    const ushort4 u = *reinterpret_cast<const ushort4*>(
        &h2[(base + n) * HDIM + cc * 128 + c4]);
    a0 += a * bf2f(u.x);
    a1 += a * bf2f(u.y);
    a2 += a * bf2f(u.z);
    a3 += a * bf2f(u.w);
  }
  __shared__ float pb[8][128];
  pb[sub][c4 + 0] = a0;
  pb[sub][c4 + 1] = a1;
  pb[sub][c4 + 2] = a2;
  pb[sub][c4 + 3] = a3;
  __syncthreads();
  if (tid < 128) {
    float s = 0.f;
#pragma unroll
    for (int j = 0; j < 8; j++) s += pb[j][tid];
    part[(size_t)nch * 8192 + b * 512 + cc * 128 + tid] = s;
  }
}

__global__ void pooled_reduce(const float* __restrict__ part,
                              float* __restrict__ pooled) {
  const int i = blockIdx.x * 256 + threadIdx.x;  // 8192 total
  float s = 0.f;
#pragma unroll
  for (int j = 0; j < 8; j++) s += part[(size_t)j * 8192 + i];
  pooled[i] = s;
}

// ---------------------------------------------------------------------------
// classifier
// ---------------------------------------------------------------------------
__global__ void classifier(const float* __restrict__ pooled,
                           const float* __restrict__ Wc1,
                           const float* __restrict__ bc1,
                           const float* __restrict__ Wc2,
                           const float* __restrict__ bc2,
                           float* __restrict__ out) {
  __shared__ float P[NBAG][512];
  __shared__ float Rb[NBAG][512];
  const int tid = threadIdx.x;  // 512
#pragma unroll
  for (int i = 0; i < NBAG; i++) P[i][tid] = pooled[i * 512 + tid];
  __syncthreads();
  float r[NBAG];
#pragma unroll
  for (int i = 0; i < NBAG; i++) r[i] = 0.f;
  for (int k = 0; k < 512; k++) {
    const float wv = Wc1[k * 512 + tid];
#pragma unroll
    for (int i = 0; i < NBAG; i++) r[i] += P[i][k] * wv;
  }
#pragma unroll
  for (int i = 0; i < NBAG; i++) Rb[i][tid] = fmaxf(r[i] + bc1[tid], 0.f);
  __syncthreads();
  if (tid < 32) {
    const int i = tid >> 1, c = tid & 1;
    float s = bc2[c];
    for (int k = 0; k < 512; k++) s += Rb[i][k] * Wc2[k * 2 + c];
    out[i * 2 + c] = s;
  }
}

// ---------------------------------------------------------------------------
extern "C" void kernel_launch(void* const* d_in, const int* in_sizes, int n_in,
                              void* d_out, int out_size, void* d_ws,
                              size_t ws_size, hipStream_t stream) {
  const float* x   = (const float*)d_in[0];
  const float* W1  = (const float*)d_in[1];
  const float* b1  = (const float*)d_in[2];
  const float* g1  = (const float*)d_in[3];
  const float* be1 = (const float*)d_in[4];
  const float* W2  = (const float*)d_in[5];
  const float* b2  = (const float*)d_in[6];
  const float* g2  = (const float*)d_in[7];
  const float* be2 = (const float*)d_in[8];
  const float* Wa1 = (const float*)d_in[9];
  const float* ba1 = (const float*)d_in[10];
  const float* wa2 = (const float*)d_in[11];
  const float* ba2 = (const float*)d_in[12];
  const float* Wc1 = (const float*)d_in[13];
  const float* bc1 = (const float*)d_in[14];
  const float* Wc2 = (const float*)d_in[15];
  const float* bc2 = (const float*)d_in[16];
  float* out = (float*)d_out;

  char* ws = (char*)d_ws;
  __hip_bfloat16* W1T = (__hip_bfloat16*)(ws + 0);          // 1 MB
  __hip_bfloat16* W2T = (__hip_bfloat16*)(ws + 1048576);    // 512 KB
  __hip_bfloat16* WaT = (__hip_bfloat16*)(ws + 1572864);    // 512 KB
  float2* statp  = (float2*)(ws + 2097152);                 // 2 MB
  float* scorep  = (float*)(ws + 4194304);                  // 1 MB
  float* attn    = (float*)(ws + 5242880);                  // 256 KB
  float* part    = (float*)(ws + 5505024);                  // 256 KB
  float* pooled  = (float*)(ws + 5767168);                  // 32 KB
  __hip_bfloat16* buf1 = (__hip_bfloat16*)(ws + 8388608);   // 64 MB (y1/h1)
  __hip_bfloat16* buf2 = (__hip_bfloat16*)(ws + 75497472);  // 64 MB (y2/h2)

  transpose_cast<<<dim3(16, 32), dim3(32, 8), 0, stream>>>(W1, W1T, DDIM, HDIM);
  transpose_cast<<<dim3(16, 16), dim3(32, 8), 0, stream>>>(W2, W2T, HDIM, HDIM);
  transpose_cast<<<dim3(16, 16), dim3(32, 8), 0, stream>>>(Wa1, WaT, HDIM, HDIM);

  const int grid = (MTOT / BM) * (HDIM / BN);  // 512 * 4 = 2048

  // GEMM1: y1 = x @ W1 + b1 (bf16) + stats  (f32 A fused-cast)
  gemm_tile<DDIM, true, 0><<<grid, 256, 0, stream>>>(
      x, W1T, b1, buf1, statp, nullptr, nullptr);
  ln_apply<<<MTOT / 4, 256, 0, stream>>>(buf1, statp, g1, be1);

  // GEMM2: y2 = h1 @ W2 + b2 (bf16) + stats
  gemm_tile<HDIM, false, 0><<<grid, 256, 0, stream>>>(
      buf1, W2T, b2, buf2, statp, nullptr, nullptr);
  ln_apply<<<MTOT / 4, 256, 0, stream>>>(buf2, statp, g2, be2);

  // GEMM3: partial scores = sum tanh(h2 @ Wa1 + ba1) * wa2
  gemm_tile<HDIM, false, 1><<<grid, 256, 0, stream>>>(
      buf2, WaT, ba1, nullptr, nullptr, wa2, scorep);

  softmax_bag<<<NBAG, 256, 0, stream>>>(scorep, ba2, attn);
  pooled_partial<<<512, 256, 0, stream>>>(buf2, attn, part);
  pooled_reduce<<<32, 256, 0, stream>>>(part, pooled);
  classifier<<<1, 512, 0, stream>>>(pooled, Wc1, bc1, Wc2, bc2, out);
}